// Round 1
// baseline (85.525 us; speedup 1.0000x reference)
//
#include <hip/hip_runtime.h>

using u16 = unsigned short;
using u32 = unsigned int;

typedef __attribute__((ext_vector_type(8))) _Float16 f16x8;
typedef __attribute__((ext_vector_type(4))) float    f32x4;

// ---------------------------------------------------------------------------
// prep 1: x (f32, 65536x256 row-major) -> f16, same layout. 8 elems/thread.
// ---------------------------------------------------------------------------
__global__ __launch_bounds__(256) void cast_x_f16(const float4* __restrict__ x4,
                                                  uint4* __restrict__ o4) {
    int t = blockIdx.x * 256 + threadIdx.x;          // 2,097,152 threads
    float4 a = x4[2 * t];
    float4 b = x4[2 * t + 1];
    union { f16x8 h; uint4 u; } cv;
    cv.h[0] = (_Float16)a.x; cv.h[1] = (_Float16)a.y;
    cv.h[2] = (_Float16)a.z; cv.h[3] = (_Float16)a.w;
    cv.h[4] = (_Float16)b.x; cv.h[5] = (_Float16)b.y;
    cv.h[6] = (_Float16)b.z; cv.h[7] = (_Float16)b.w;
    o4[t] = cv.u;
}

// ---------------------------------------------------------------------------
// prep 2: WcatT[n][kk] = s(i,kb) * W[c][(i^kb)*256 + u]   (f16, 1024x1024)
//   n  = kb*256 + u   (output blade kb, unit u)
//   kk = i*256  + c   (input blade i, channel c)
// sign bits packed: bit (4*i + kb) of 0x3950
//   i=0: ++++  i=1: -+-+  i=2: -++-  i=3: --++
// ---------------------------------------------------------------------------
__global__ __launch_bounds__(256) void build_wcatT(const float* __restrict__ W,
                                                   _Float16* __restrict__ Wt) {
    int t  = blockIdx.x * 256 + threadIdx.x;         // 1,048,576 threads
    int n  = t >> 10, kk = t & 1023;
    int kb = n >> 8,  u  = n & 255;
    int i  = kk >> 8, c  = kk & 255;
    int j  = i ^ kb;
    float v = W[c * 1024 + j * 256 + u];
    if ((0x3950u >> (i * 4 + kb)) & 1u) v = -v;
    Wt[t] = (_Float16)v;
}

// ---------------------------------------------------------------------------
// GEMM: C[b, n] = sum_kk Xcat[b,kk] * WcatT[n,kk];  out[(n>>8)*16384+b, n&255]
//   M=16384, N=1024, K=1024. 128x128 tile, BK=64, 4 waves (2x2), m97 structure.
// ---------------------------------------------------------------------------
__device__ __forceinline__ void async16(const void* g, void* l) {
    __builtin_amdgcn_global_load_lds((const __attribute__((address_space(1))) u32*)g,
                                     (__attribute__((address_space(3))) u32*)l,
                                     16, 0, 0);
}

__global__ __launch_bounds__(256) void ga_gemm(const _Float16* __restrict__ A,   // xh: (i*16384+m)*256 + c
                                               const _Float16* __restrict__ Bt,  // WcatT: n*1024 + kk
                                               const float*  __restrict__ bias,  // 1024
                                               float* __restrict__ out) {        // 65536x256
    __shared__ _Float16 As[128 * 64] __attribute__((aligned(16)));  // [m][k] 16 KB
    __shared__ _Float16 Bs[128 * 64] __attribute__((aligned(16)));  // [n][k] 16 KB

    const int tid  = threadIdx.x;
    const int lane = tid & 63;
    const int wm   = (tid >> 6) >> 1;   // wave row 0..1
    const int wn   = (tid >> 6) & 1;    // wave col 0..1
    const int l15  = lane & 15;
    const int lg   = lane >> 4;

    const int mt = blockIdx.x >> 3;     // 128 m-tiles
    const int nt = blockIdx.x & 7;      // 8 n-tiles
    const int m0 = mt * 128;
    const int n0 = nt * 128;

    const int srow = tid >> 3;          // staging: row 0..31 per issue
    const int scol = (tid & 7) * 8;     // staging: 8-elem (16B) chunk in 64-wide row

    f32x4 acc[4][4] = {};

    for (int kt = 0; kt < 16; ++kt) {
        const int k0 = kt * 64;
        const int ib = k0 >> 8;         // input blade of this K-tile
        const int c0 = k0 & 255;        // channel offset within blade
        const _Float16* gA = A  + (size_t)(ib * 16384 + m0 + srow) * 256 + c0 + scol;
        const _Float16* gB = Bt + (size_t)(n0 + srow) * 1024 + k0 + scol;
        _Float16* lA = As + tid * 8;    // lane-linear LDS dest (base + lane*16B)
        _Float16* lB = Bs + tid * 8;
#pragma unroll
        for (int it = 0; it < 4; ++it) {
            async16(gA + it * 32 * 256,  lA + it * 2048);
            async16(gB + it * 32 * 1024, lB + it * 2048);
        }
        __syncthreads();                // compiler drains vmcnt(0) before barrier
#pragma unroll
        for (int kk = 0; kk < 2; ++kk) {
            const int koff = kk * 32 + lg * 8;   // A/B frag: k = 8*(lane>>4)+i
            f16x8 af[4], bfv[4];
#pragma unroll
            for (int f = 0; f < 4; ++f) {
                af[f]  = *(const f16x8*)(As + (wm * 64 + f * 16 + l15) * 64 + koff);
                bfv[f] = *(const f16x8*)(Bs + (wn * 64 + f * 16 + l15) * 64 + koff);
            }
#pragma unroll
            for (int fm = 0; fm < 4; ++fm)
#pragma unroll
                for (int fn = 0; fn < 4; ++fn)
                    acc[fm][fn] = __builtin_amdgcn_mfma_f32_16x16x32_f16(
                                      af[fm], bfv[fn], acc[fm][fn], 0, 0, 0);
        }
        __syncthreads();
    }

    // epilogue: C/D layout col=lane&15, row=(lane>>4)*4+r (HW-verified m89/m91)
#pragma unroll
    for (int fn = 0; fn < 4; ++fn) {
        const int n  = n0 + wn * 64 + fn * 16 + l15;
        const int kb = n >> 8;
        const int u  = n & 255;
        const float bv = bias[n];
#pragma unroll
        for (int fm = 0; fm < 4; ++fm) {
            const int mb = m0 + wm * 64 + fm * 16 + lg * 4;
            float* op = out + (size_t)(kb * 16384 + mb) * 256 + u;
#pragma unroll
            for (int r = 0; r < 4; ++r)
                op[(size_t)r * 256] = acc[fm][fn][r] + bv;
        }
    }
}

// ---------------------------------------------------------------------------
extern "C" void kernel_launch(void* const* d_in, const int* in_sizes, int n_in,
                              void* d_out, int out_size, void* d_ws, size_t ws_size,
                              hipStream_t stream) {
    (void)in_sizes; (void)n_in; (void)out_size; (void)ws_size;
    const float* x = (const float*)d_in[0];   // (65536, 256)
    const float* W = (const float*)d_in[1];   // (256, 1024)
    const float* b = (const float*)d_in[2];   // (1024,)
    float* out = (float*)d_out;               // (65536, 256)

    _Float16* Wt = (_Float16*)d_ws;                                   // 2 MB
    _Float16* xh = (_Float16*)((char*)d_ws + (size_t)(2u << 20));     // 32 MB

    build_wcatT<<<4096, 256, 0, stream>>>(W, Wt);
    cast_x_f16<<<8192, 256, 0, stream>>>((const float4*)x, (uint4*)xh);
    ga_gemm<<<1024, 256, 0, stream>>>(xh, Wt, b, out);
}

// Round 2
// 65.701 us; speedup vs baseline: 1.3017x; 1.3017x over previous
//
#include <hip/hip_runtime.h>

using u32 = unsigned int;

typedef __attribute__((ext_vector_type(8))) _Float16 f16x8;
typedef __attribute__((ext_vector_type(4))) float    f32x4;

// ---------------------------------------------------------------------------
// prep 1: x (f32, 65536x256 row-major) -> f16, same layout. 8 elems/thread.
// ---------------------------------------------------------------------------
__global__ __launch_bounds__(256) void cast_x_f16(const float4* __restrict__ x4,
                                                  uint4* __restrict__ o4) {
    int t = blockIdx.x * 256 + threadIdx.x;          // 2,097,152 threads
    float4 a = x4[2 * t];
    float4 b = x4[2 * t + 1];
    union { f16x8 h; uint4 u; } cv;
    cv.h[0] = (_Float16)a.x; cv.h[1] = (_Float16)a.y;
    cv.h[2] = (_Float16)a.z; cv.h[3] = (_Float16)a.w;
    cv.h[4] = (_Float16)b.x; cv.h[5] = (_Float16)b.y;
    cv.h[6] = (_Float16)b.z; cv.h[7] = (_Float16)b.w;
    o4[t] = cv.u;
}

// ---------------------------------------------------------------------------
// prep 2: WcatT[n][kk] = s(i,kb) * W[c][(i^kb)*256 + u]   (f16, 1024x1024)
// sign bits packed: bit (4*i + kb) of 0x3950
// ---------------------------------------------------------------------------
__global__ __launch_bounds__(256) void build_wcatT(const float* __restrict__ W,
                                                   _Float16* __restrict__ Wt) {
    int t  = blockIdx.x * 256 + threadIdx.x;         // 1,048,576 threads
    int n  = t >> 10, kk = t & 1023;
    int kb = n >> 8,  u  = n & 255;
    int i  = kk >> 8, c  = kk & 255;
    int j  = i ^ kb;
    float v = W[c * 1024 + j * 256 + u];
    if ((0x3950u >> (i * 4 + kb)) & 1u) v = -v;
    Wt[t] = (_Float16)v;
}

// ---------------------------------------------------------------------------
// GEMM: C[b, n] = sum_kk Xcat[b,kk] * WcatT[n,kk]
//   M=16384, N=1024, K=1024.  256x256 tile, BK=32, 4 LDS sub-buffers,
//   8 waves (2M x 4N), 2 phases/K-tile, counted vmcnt(8) pipeline,
//   T2 swizzle (chunk ^= (row>>1)&3), T5 setprio, XCD-aware block swizzle.
// ---------------------------------------------------------------------------
__device__ __forceinline__ void async16(const void* g, void* l) {
    __builtin_amdgcn_global_load_lds((const __attribute__((address_space(1))) u32*)g,
                                     (__attribute__((address_space(3))) u32*)l,
                                     16, 0, 0);
}

#define BARRIER() do { asm volatile("" ::: "memory"); \
                       __builtin_amdgcn_s_barrier(); \
                       asm volatile("" ::: "memory"); } while (0)

#define VMW(n) asm volatile("s_waitcnt vmcnt(" #n ")" ::: "memory")

#define MFMA(av, bv, c) __builtin_amdgcn_mfma_f32_16x16x32_f16(av, bv, c, 0, 0, 0)

// one 16-MFMA cluster: m-frags f0..f3 x n-frags 0..3, K=32
#define PHASE_MFMA(f0, f1, f2, f3) do { \
    __builtin_amdgcn_s_setprio(1); \
    acc[f0][0]=MFMA(a0,b0,acc[f0][0]); acc[f0][1]=MFMA(a0,b1,acc[f0][1]); \
    acc[f0][2]=MFMA(a0,b2,acc[f0][2]); acc[f0][3]=MFMA(a0,b3,acc[f0][3]); \
    acc[f1][0]=MFMA(a1,b0,acc[f1][0]); acc[f1][1]=MFMA(a1,b1,acc[f1][1]); \
    acc[f1][2]=MFMA(a1,b2,acc[f1][2]); acc[f1][3]=MFMA(a1,b3,acc[f1][3]); \
    acc[f2][0]=MFMA(a2,b0,acc[f2][0]); acc[f2][1]=MFMA(a2,b1,acc[f2][1]); \
    acc[f2][2]=MFMA(a2,b2,acc[f2][2]); acc[f2][3]=MFMA(a2,b3,acc[f2][3]); \
    acc[f3][0]=MFMA(a3,b0,acc[f3][0]); acc[f3][1]=MFMA(a3,b1,acc[f3][1]); \
    acc[f3][2]=MFMA(a3,b2,acc[f3][2]); acc[f3][3]=MFMA(a3,b3,acc[f3][3]); \
    __builtin_amdgcn_s_setprio(0); \
    __builtin_amdgcn_sched_barrier(0); \
} while (0)

// stage K-tile u's A half (2 x 16B/thread) into buf[u&3]; source pre-swizzled
#define STAGE_A(u) do { \
    const int _b = ((u) & 3) * 16384; \
    const size_t _g = (size_t)((u) >> 3) * 4194304 + ((u) & 7) * 32; \
    async16(gA0 + _g, lds + _b + tid * 8); \
    async16(gA1 + _g, lds + _b + 4096 + tid * 8); \
} while (0)

#define STAGE_B(u) do { \
    const int _b = ((u) & 3) * 16384 + 8192; \
    const int _g = (u) * 32; \
    async16(gB0 + _g, lds + _b + tid * 8); \
    async16(gB1 + _g, lds + _b + 4096 + tid * 8); \
} while (0)

// one K-tile: 2 phases x {ds_read, stage-issue, barrier, 16 MFMA, barrier}
#define TILE(t, DO_STAGE, GATE) do { \
    const _Float16* Ab = lds + ((t) & 3) * 16384; \
    const _Float16* Bb = Ab + 8192; \
    f16x8 a0, a1, a2, a3, b0, b1, b2, b3; \
    a0 = *(const f16x8*)(Ab + aoff);        a1 = *(const f16x8*)(Ab + aoff + 512); \
    a2 = *(const f16x8*)(Ab + aoff + 1024); a3 = *(const f16x8*)(Ab + aoff + 1536); \
    b0 = *(const f16x8*)(Bb + boff);        b1 = *(const f16x8*)(Bb + boff + 512); \
    b2 = *(const f16x8*)(Bb + boff + 1024); b3 = *(const f16x8*)(Bb + boff + 1536); \
    if (DO_STAGE) { STAGE_A((t) + 3); } \
    BARRIER(); \
    PHASE_MFMA(0, 1, 2, 3); \
    BARRIER(); \
    a0 = *(const f16x8*)(Ab + aoff + 2048); a1 = *(const f16x8*)(Ab + aoff + 2560); \
    a2 = *(const f16x8*)(Ab + aoff + 3072); a3 = *(const f16x8*)(Ab + aoff + 3584); \
    if (DO_STAGE) { STAGE_B((t) + 3); } \
    BARRIER(); \
    PHASE_MFMA(4, 5, 6, 7); \
    GATE; \
    BARRIER(); \
} while (0)

__global__ __launch_bounds__(512, 2) void ga_gemm(const _Float16* __restrict__ A,   // xh
                                                  const _Float16* __restrict__ Bt,  // WcatT
                                                  const float*  __restrict__ bias,  // 1024
                                                  float* __restrict__ out) {        // 65536x256
    __shared__ _Float16 lds[4 * 16384] __attribute__((aligned(16)));  // 128 KiB

    const int tid  = threadIdx.x;
    const int lane = tid & 63;
    const int wid  = tid >> 6;          // 0..7
    const int wm   = wid >> 2;          // 0..1  (M half)
    const int wn   = wid & 3;           // 0..3  (N quarter)
    const int l15  = lane & 15;
    const int lg   = lane >> 4;

    // XCD-aware bijective swizzle: 256 blocks, 8 XCDs, 32 contiguous each
    const int bid = blockIdx.x;
    const int swz = (bid & 7) * 32 + (bid >> 3);
    const int mt  = swz >> 2, nt = swz & 3;    // 64 m-tiles x 4 n-tiles
    const int m0  = mt * 256,  n0 = nt * 256;

    // staging: slot s = it*512 + tid -> (row = s>>2, chunk = s&3); source
    // chunk pre-swizzled so LDS slot (row,c) holds global chunk c^((row>>1)&3)
    const int s1 = 512 + tid;
    const int r0 = tid >> 2,        r1 = s1 >> 2;
    const int g0 = (tid & 3) ^ ((r0 >> 1) & 3);
    const int g1 = (s1 & 3) ^ ((r1 >> 1) & 3);
    const _Float16* gA0 = A  + (size_t)(m0 + r0) * 256  + g0 * 8;
    const _Float16* gA1 = A  + (size_t)(m0 + r1) * 256  + g1 * 8;
    const _Float16* gB0 = Bt + (size_t)(n0 + r0) * 1024 + g0 * 8;
    const _Float16* gB1 = Bt + (size_t)(n0 + r1) * 1024 + g1 * 8;

    // ds_read fragment offsets (f16 units), swizzled chunk per thread
    const int sc   = lg ^ ((l15 >> 1) & 3);
    const int aoff = (wm * 128 + l15) * 32 + sc * 8;
    const int boff = (wn * 64  + l15) * 32 + sc * 8;

    f32x4 acc[8][4] = {};

    // prologue: stage tiles 0,1,2 (12 loads); gate tile 0 (8 outstanding ok)
    STAGE_A(0); STAGE_B(0);
    STAGE_A(1); STAGE_B(1);
    STAGE_A(2); STAGE_B(2);
    VMW(8);
    BARRIER();

    for (int t = 0; t < 29; ++t) {
        TILE(t, 1, VMW(8));
    }
    TILE(29, 0, VMW(4));
    TILE(30, 0, VMW(0));
    TILE(31, 0, (void)0);

    // epilogue: C/D layout col=lane&15, row=(lane>>4)*4+r
    const size_t outBase = (size_t)(nt * 16384) * 256;   // output blade offset
    const int ucol = wn * 64 + l15;
    float bv[4];
#pragma unroll
    for (int fn = 0; fn < 4; ++fn) bv[fn] = bias[nt * 256 + ucol + fn * 16];
#pragma unroll
    for (int fm = 0; fm < 8; ++fm) {
        const int m = m0 + wm * 128 + fm * 16 + lg * 4;
#pragma unroll
        for (int r = 0; r < 4; ++r) {
            float* op = out + outBase + (size_t)(m + r) * 256;
#pragma unroll
            for (int fn = 0; fn < 4; ++fn)
                op[ucol + fn * 16] = acc[fm][fn][r] + bv[fn];
        }
    }
}

// ---------------------------------------------------------------------------
extern "C" void kernel_launch(void* const* d_in, const int* in_sizes, int n_in,
                              void* d_out, int out_size, void* d_ws, size_t ws_size,
                              hipStream_t stream) {
    (void)in_sizes; (void)n_in; (void)out_size; (void)ws_size;
    const float* x = (const float*)d_in[0];   // (65536, 256)
    const float* W = (const float*)d_in[1];   // (256, 1024)
    const float* b = (const float*)d_in[2];   // (1024,)
    float* out = (float*)d_out;               // (65536, 256)

    _Float16* Wt = (_Float16*)d_ws;                                   // 2 MB
    _Float16* xh = (_Float16*)((char*)d_ws + (size_t)(2u << 20));     // 32 MB

    build_wcatT<<<4096, 256, 0, stream>>>(W, Wt);
    cast_x_f16<<<8192, 256, 0, stream>>>((const float4*)x, (uint4*)xh);
    ga_gemm<<<256, 512, 0, stream>>>(xh, Wt, b, out);
}

// Round 4
// 54.718 us; speedup vs baseline: 1.5630x; 1.2007x over previous
//
#include <hip/hip_runtime.h>

using u32 = unsigned int;

typedef __attribute__((ext_vector_type(8))) _Float16 f16x8;
typedef __attribute__((ext_vector_type(4))) float    f32x4;

// ---------------------------------------------------------------------------
// prep: WcatT[n][kk] = s(i,kb) * W[c][(i^kb)*256 + u]   (f16, 1024x1024)
// sign bits packed: bit (4*i + kb) of 0x3950
// ---------------------------------------------------------------------------
__global__ __launch_bounds__(256) void build_wcatT(const float* __restrict__ W,
                                                   _Float16* __restrict__ Wt) {
    int t  = blockIdx.x * 256 + threadIdx.x;         // 1,048,576 threads
    int n  = t >> 10, kk = t & 1023;
    int kb = n >> 8,  u  = n & 255;
    int i  = kk >> 8, c  = kk & 255;
    int j  = i ^ kb;
    float v = W[c * 1024 + j * 256 + u];
    if ((0x3950u >> (i * 4 + kb)) & 1u) v = -v;
    Wt[t] = (_Float16)v;
}

// ---------------------------------------------------------------------------
// GEMM with fused f32->f16 A-cast:
//   C[b, n] = sum_kk (f16)x[b,kk] * WcatT[n,kk],  M=16384, N=1024, K=1024
//   256x256 tile, BK=32, 4 LDS sub-buffers, 8 waves (2M x 4N).
//   A: reg-staged (4x global_load_dwordx4 asm -> cvt -> 2x swizzled ds_write).
//   B: global_load_lds, pre-swizzled source. Counted vmcnt(6) pipeline.
// ---------------------------------------------------------------------------
__device__ __forceinline__ void async16(const void* g, void* l) {
    __builtin_amdgcn_global_load_lds((const __attribute__((address_space(1))) u32*)g,
                                     (__attribute__((address_space(3))) u32*)l,
                                     16, 0, 0);
}

#define BARRIER() do { asm volatile("" ::: "memory"); \
                       __builtin_amdgcn_s_barrier(); \
                       asm volatile("" ::: "memory"); } while (0)

#define VMW(n)  asm volatile("s_waitcnt vmcnt(" #n ")" ::: "memory")
#define LGKM0() asm volatile("s_waitcnt lgkmcnt(0)" ::: "memory")
#define SB0()   __builtin_amdgcn_sched_barrier(0)

// 16B global load into regs; dst MUST be ext_vector f32x4; offset literal bytes
#define GL16(dst, ptr, off) \
    asm volatile("global_load_dwordx4 %0, %1, off offset:" #off \
                 : "=v"(dst) : "v"(ptr))

#define MFMA(av, bv, c) __builtin_amdgcn_mfma_f32_16x16x32_f16(av, bv, c, 0, 0, 0)

#define PHASE_MFMA(f0, f1, f2, f3) do { \
    __builtin_amdgcn_s_setprio(1); \
    acc[f0][0]=MFMA(a0,b0,acc[f0][0]); acc[f0][1]=MFMA(a0,b1,acc[f0][1]); \
    acc[f0][2]=MFMA(a0,b2,acc[f0][2]); acc[f0][3]=MFMA(a0,b3,acc[f0][3]); \
    acc[f1][0]=MFMA(a1,b0,acc[f1][0]); acc[f1][1]=MFMA(a1,b1,acc[f1][1]); \
    acc[f1][2]=MFMA(a1,b2,acc[f1][2]); acc[f1][3]=MFMA(a1,b3,acc[f1][3]); \
    acc[f2][0]=MFMA(a2,b0,acc[f2][0]); acc[f2][1]=MFMA(a2,b1,acc[f2][1]); \
    acc[f2][2]=MFMA(a2,b2,acc[f2][2]); acc[f2][3]=MFMA(a2,b3,acc[f2][3]); \
    acc[f3][0]=MFMA(a3,b0,acc[f3][0]); acc[f3][1]=MFMA(a3,b1,acc[f3][1]); \
    acc[f3][2]=MFMA(a3,b2,acc[f3][2]); acc[f3][3]=MFMA(a3,b3,acc[f3][3]); \
    __builtin_amdgcn_s_setprio(0); \
    __builtin_amdgcn_sched_barrier(0); \
} while (0)

// B K-tile u -> buf[u&3] (2 x 16B/thread via global_load_lds, source pre-swz)
#define STAGE_B(u) do { \
    const int _b = ((u) & 3) * 16384 + 8192; \
    const int _g = (u) * 32; \
    async16(gB0 + _g, lds + _b + tid * 8); \
    async16(gB1 + _g, lds + _b + 4096 + tid * 8); \
} while (0)

// issue 4 A f32 loads for K-tile u into regs d0..d3 (64 B contiguous/thread)
#define ISSUE_A(u, d0, d1, d2, d3) do { \
    const float* _p = pA + (size_t)((u) >> 3) * 4194304 + ((u) & 7) * 32; \
    GL16(d0, _p, 0); GL16(d1, _p, 16); GL16(d2, _p, 32); GL16(d3, _p, 48); \
} while (0)

// cvt 16 f32 -> f16, write 2 swizzled b128 chunks into buf BUFW's A region
#define WRITE_A(BUFW, s0, s1, s2, s3) do { \
    f16x8 h0, h1; \
    h0[0]=(_Float16)(s0)[0]; h0[1]=(_Float16)(s0)[1]; h0[2]=(_Float16)(s0)[2]; h0[3]=(_Float16)(s0)[3]; \
    h0[4]=(_Float16)(s1)[0]; h0[5]=(_Float16)(s1)[1]; h0[6]=(_Float16)(s1)[2]; h0[7]=(_Float16)(s1)[3]; \
    h1[0]=(_Float16)(s2)[0]; h1[1]=(_Float16)(s2)[1]; h1[2]=(_Float16)(s2)[2]; h1[3]=(_Float16)(s2)[3]; \
    h1[4]=(_Float16)(s3)[0]; h1[5]=(_Float16)(s3)[1]; h1[6]=(_Float16)(s3)[2]; h1[7]=(_Float16)(s3)[3]; \
    _Float16* _wp = lds + (BUFW) * 16384 + wrow * 32; \
    *(f16x8*)(_wp + wc0 * 8) = h0; \
    *(f16x8*)(_wp + wc1 * 8) = h1; \
} while (0)

// one K-tile: phase1 {ds_read half1, issue A(t+3)} MFMA, phase2 {ds_read half2,
// stage B(t+3)} MFMA, then GATE -> cvt+write A(t+2) -> lgkm -> barrier
#define TILE(T, BUF, DO_ISSUE, I0,I1,I2,I3, DO_WRITE, W0,W1,W2,W3, GATE) do { \
    const _Float16* Ab = lds + (BUF) * 16384; \
    const _Float16* Bb = Ab + 8192; \
    f16x8 a0, a1, a2, a3, b0, b1, b2, b3; \
    a0 = *(const f16x8*)(Ab + aoff);        a1 = *(const f16x8*)(Ab + aoff + 512); \
    a2 = *(const f16x8*)(Ab + aoff + 1024); a3 = *(const f16x8*)(Ab + aoff + 1536); \
    b0 = *(const f16x8*)(Bb + boff);        b1 = *(const f16x8*)(Bb + boff + 512); \
    b2 = *(const f16x8*)(Bb + boff + 1024); b3 = *(const f16x8*)(Bb + boff + 1536); \
    if (DO_ISSUE) { ISSUE_A((T) + 3, I0, I1, I2, I3); } \
    BARRIER(); \
    PHASE_MFMA(0, 1, 2, 3); \
    BARRIER(); \
    a0 = *(const f16x8*)(Ab + aoff + 2048); a1 = *(const f16x8*)(Ab + aoff + 2560); \
    a2 = *(const f16x8*)(Ab + aoff + 3072); a3 = *(const f16x8*)(Ab + aoff + 3584); \
    if (DO_ISSUE) { STAGE_B((T) + 3); } \
    BARRIER(); \
    PHASE_MFMA(4, 5, 6, 7); \
    GATE; \
    SB0(); \
    if (DO_WRITE) { WRITE_A((((T) + 2) & 3), W0, W1, W2, W3); } \
    LGKM0(); \
    BARRIER(); \
} while (0)

__global__ __launch_bounds__(512, 2) void ga_gemm(const float* __restrict__ A,    // x f32
                                                  const _Float16* __restrict__ Bt,// WcatT
                                                  const float*  __restrict__ bias,
                                                  float* __restrict__ out) {
    __shared__ _Float16 lds[4 * 16384] __attribute__((aligned(16)));  // 128 KiB

    const int tid  = threadIdx.x;
    const int lane = tid & 63;
    const int wid  = tid >> 6;
    const int wm   = wid >> 2;          // 0..1
    const int wn   = wid & 3;           // 0..3
    const int l15  = lane & 15;
    const int lg   = lane >> 4;

    // XCD-aware bijective swizzle: 256 blocks, 8 XCDs, 32 contiguous each
    const int bid = blockIdx.x;
    const int swz = (bid & 7) * 32 + (bid >> 3);
    const int mt  = swz >> 2, nt = swz & 3;
    const int m0  = mt * 256,  n0 = nt * 256;

    // A reg-staging map: thread -> (row, half-row of 16 f32)
    const int wrow  = tid >> 1;          // 0..255
    const int whalf = tid & 1;
    const int wsw   = (wrow >> 1) & 3;
    const int wc0   = (whalf * 2) ^ wsw;       // swizzled 16B-chunk slots
    const int wc1   = (whalf * 2 + 1) ^ wsw;
    const float* pA = A + (size_t)(m0 + wrow) * 256 + whalf * 16;

    // B staging map (slot s -> row s>>2, chunk s&3; source pre-swizzled)
    const int s1 = 512 + tid;
    const int r0 = tid >> 2,  r1 = s1 >> 2;
    const int g0 = (tid & 3) ^ ((r0 >> 1) & 3);
    const int g1 = (s1 & 3)  ^ ((r1 >> 1) & 3);
    const _Float16* gB0 = Bt + (size_t)(n0 + r0) * 1024 + g0 * 8;
    const _Float16* gB1 = Bt + (size_t)(n0 + r1) * 1024 + g1 * 8;

    // ds_read fragment offsets (f16 units), swizzled chunk per thread
    const int sc   = lg ^ ((l15 >> 1) & 3);
    const int aoff = (wm * 128 + l15) * 32 + sc * 8;
    const int boff = (wn * 64  + l15) * 32 + sc * 8;

    f32x4 acc[8][4] = {};
    f32x4 u0, u1, u2, u3, v0, v1, v2, v3;

    // prologue: tiles 0,1 staged+written; tile 2 in flight (A in V, B in LDS)
    ISSUE_A(0, u0, u1, u2, u3);  STAGE_B(0);
    ISSUE_A(1, v0, v1, v2, v3);  STAGE_B(1);
    VMW(8);  SB0();
    WRITE_A(0, u0, u1, u2, u3);
    VMW(0);  SB0();
    WRITE_A(1, v0, v1, v2, v3);
    LGKM0();                      // drain ds_writes sourcing v before re-issue
    ISSUE_A(2, v0, v1, v2, v3);  STAGE_B(2);
    LGKM0();
    BARRIER();

    for (int t = 0; t < 28; t += 2) {
        TILE(t,     (t) & 3,     1, u0,u1,u2,u3, 1, v0,v1,v2,v3, VMW(6));
        TILE(t + 1, (t + 1) & 3, 1, v0,v1,v2,v3, 1, u0,u1,u2,u3, VMW(6));
    }
    TILE(28, 0, 1, u0,u1,u2,u3, 1, v0,v1,v2,v3, VMW(6));
    TILE(29, 1, 0, u0,u1,u2,u3, 1, u0,u1,u2,u3, VMW(0));
    TILE(30, 2, 0, u0,u1,u2,u3, 0, u0,u1,u2,u3, (void)0);
    TILE(31, 3, 0, u0,u1,u2,u3, 0, u0,u1,u2,u3, (void)0);

    // epilogue: C/D layout col=lane&15, row=(lane>>4)*4+r
    const size_t outBase = (size_t)(nt * 16384) * 256;
    const int ucol = wn * 64 + l15;
    float bv[4];
#pragma unroll
    for (int fn = 0; fn < 4; ++fn) bv[fn] = bias[nt * 256 + ucol + fn * 16];
#pragma unroll
    for (int fm = 0; fm < 8; ++fm) {
        const int m = m0 + wm * 128 + fm * 16 + lg * 4;
#pragma unroll
        for (int r = 0; r < 4; ++r) {
            float* op = out + outBase + (size_t)(m + r) * 256;
#pragma unroll
            for (int fn = 0; fn < 4; ++fn)
                op[ucol + fn * 16] = acc[fm][fn][r] + bv[fn];
        }
    }
}

// ---------------------------------------------------------------------------
extern "C" void kernel_launch(void* const* d_in, const int* in_sizes, int n_in,
                              void* d_out, int out_size, void* d_ws, size_t ws_size,
                              hipStream_t stream) {
    (void)in_sizes; (void)n_in; (void)out_size; (void)ws_size;
    const float* x = (const float*)d_in[0];   // (65536, 256)
    const float* W = (const float*)d_in[1];   // (256, 1024)
    const float* b = (const float*)d_in[2];   // (1024,)
    float* out = (float*)d_out;               // (65536, 256)

    _Float16* Wt = (_Float16*)d_ws;           // 2 MB

    build_wcatT<<<4096, 256, 0, stream>>>(W, Wt);
    ga_gemm<<<256, 512, 0, stream>>>(x, Wt, b, out);
}